// Round 1
// baseline (615.490 us; speedup 1.0000x reference)
//
#include <hip/hip_runtime.h>
#include <hip/hip_bf16.h>

// DynamicGATLayer on MI355X — R5: Adj==0 hoisted to a bitmask, L2-resident j-loop.
// B=2, N=2048, F=128, FE=8, H=4, C=64, HC=256.
//
// Simplifications (verified passing R1-R4):
//  - A * sigmoid(E.W_edge+b) == 0  <=>  A == 0 (sigmoid in (0.1,0.9)), so
//    E/W_edge/b_edge are never read.
//  - |leaky(ss+sd)| <~ 6 -> exp without max-subtraction is safe in fp32;
//    masked entries are exactly 0 both here and in the reference.
//  - ss/sd pre-scaled by log2(e): exp(leaky(x)) = exp2(leaky(x*log2e)).
//
// R5 deltas vs R4 (386.98 us; k1+k2 ~60us of that, rest is harness ws-poison):
//  - Adj values are never needed in k2 — only the (A==0) predicate (~1 exact
//    zero in 8.4M uniform entries, but must be honored). k1 now makes one
//    coalesced sweep of Adj (33.5 MB, read exactly once from HBM) and writes a
//    1-bit-per-edge mask zT (1 MB), laid out [row][jq][lq][step] so each k2
//    lane loads its whole j-loop mask as ONE 16B load before the loop.
//  - k2 j-loop: 8 -> 6 VMEM instr/step; all loop data (hT 2MB, sdT 128KB,
//    zT 1MB) is L2-resident -> ~200-300cy latency, covered by the 2-stage
//    prefetch (R4's exposed ~900cy HBM Adj stream is gone). Rare-zero masking
//    sits behind a per-lane `if(mb)` (execmask; ~2 instr on common path),
//    dropping the per-element cmp+cndmask.
//  - j-loop fully unrolled as 4x4 nest so mask bytes are compile-time-indexed
//    (avoids runtime-indexed ext_vector -> scratch).

#define BB 2
#define NN 2048
#define FF 128
#define HH 4
#define CC 64
#define HC 256
#define TN 8      // node rows per block, K1
#define LOG2E 1.4426950408889634f

typedef __attribute__((ext_vector_type(8))) short short8;
typedef __attribute__((ext_vector_type(4))) float f32x4;

__device__ __forceinline__ float wave_sum(float v) {
#pragma unroll
    for (int m = 32; m >= 1; m >>= 1) v += __shfl_xor(v, m, 64);
    return v;
}

__device__ __forceinline__ unsigned short bf16rne(float x) {
    unsigned u = __float_as_uint(x);
    return (unsigned short)((u + 0x7fffu + ((u >> 16) & 1u)) >> 16);
}

// ---------------- K1 ----------------
__global__ __launch_bounds__(256) void k1_proj(
    const float* __restrict__ X, const float* __restrict__ Adj,
    const float* __restrict__ Wg,
    const float* __restrict__ a_src, const float* __restrict__ a_dst,
    unsigned short* __restrict__ hT, float* __restrict__ ssT,
    float* __restrict__ sdT, unsigned char* __restrict__ zT)
{
    __shared__ float sX[TN][FF];
    const int blk = blockIdx.x;               // B*N/TN blocks
    const int b  = blk / (NN / TN);
    const int n0 = (blk % (NN / TN)) * TN;
    const int tid = threadIdx.x;
    const int h = tid >> 6, c = tid & 63;

    for (int idx = tid; idx < TN * FF; idx += 256) {
        int r = idx >> 7, f = idx & 127;
        sX[r][f] = X[(size_t)(b * NN + n0 + r) * FF + f];
    }
    __syncthreads();

    float hv[TN];
#pragma unroll
    for (int r = 0; r < TN; ++r) hv[r] = 0.f;

#pragma unroll 4
    for (int f4 = 0; f4 < FF / 4; ++f4) {
        const int f = f4 * 4;
        const float w0 = Wg[(h * FF + f + 0) * CC + c];
        const float w1 = Wg[(h * FF + f + 1) * CC + c];
        const float w2 = Wg[(h * FF + f + 2) * CC + c];
        const float w3 = Wg[(h * FF + f + 3) * CC + c];
#pragma unroll
        for (int r = 0; r < TN; ++r) {
            float4 x4 = *(const float4*)&sX[r][f];
            hv[r] = fmaf(x4.x, w0, hv[r]);
            hv[r] = fmaf(x4.y, w1, hv[r]);
            hv[r] = fmaf(x4.z, w2, hv[r]);
            hv[r] = fmaf(x4.w, w3, hv[r]);
        }
    }

    // hT[b][h][c][n], 8 consecutive n per thread -> one 16B store
    union { short8 v; unsigned short u[8]; } pk;
#pragma unroll
    for (int r = 0; r < TN; ++r) pk.u[r] = bf16rne(hv[r]);
    *(short8*)&hT[((size_t)(b * HH + h) * CC + c) * NN + n0] = pk.v;

    const float as = a_src[tid];
    const float ad = a_dst[tid];
#pragma unroll
    for (int r = 0; r < TN; ++r) {
        const int n = n0 + r;
        float s1 = wave_sum(hv[r] * as);
        float s2 = wave_sum(hv[r] * ad);
        if (c == 0) {
            ssT[(b * HH + h) * NN + n] = s1 * LOG2E;
            sdT[(b * HH + h) * NN + n] = s2 * LOG2E;
        }
    }

    // ---- Adj zero-bitmask sweep: rows n0..n0+7, all 2048 j ----
    // thread t: row r = t>>5, segment s = t&31 -> j in [s*64, s*64+64).
    // byte jb = j/8 stored at row-offset (jb>>6)*64 + (jb&3)*16 + ((jb&63)>>2),
    // i.e. zT[row][jq][lq][step] so a k2 lane's 16 step-bytes are contiguous.
    {
        const int r = tid >> 5;
        const int s = tid & 31;
        const size_t row = (size_t)(b * NN + n0 + r);
        const float* ap = Adj + row * NN + s * 64;
        unsigned char* zp = zT + (row << 8);
#pragma unroll
        for (int k = 0; k < 8; ++k) {
            float4 a0 = *(const float4*)(ap + k * 8);
            float4 a1 = *(const float4*)(ap + k * 8 + 4);
            unsigned m = 0u;
            m |= (a0.x == 0.f) ? 1u   : 0u;
            m |= (a0.y == 0.f) ? 2u   : 0u;
            m |= (a0.z == 0.f) ? 4u   : 0u;
            m |= (a0.w == 0.f) ? 8u   : 0u;
            m |= (a1.x == 0.f) ? 16u  : 0u;
            m |= (a1.y == 0.f) ? 32u  : 0u;
            m |= (a1.z == 0.f) ? 64u  : 0u;
            m |= (a1.w == 0.f) ? 128u : 0u;
            const int jb = s * 8 + k;
            const int jq = jb >> 6, rem = jb & 63;
            const int it = rem >> 2, lq = rem & 3;
            zp[jq * 64 + lq * 16 + it] = (unsigned char)m;
        }
    }
}

// ---------------- K2 ----------------
struct Stage {
    float4 sda, sdb;  // sd, 8 floats
    short8 bfr[4];    // hT B-frags
};

__device__ __forceinline__ void load_stage(
    Stage& s, const float* sdp, const unsigned short* const* hb, int js)
{
    s.sda = *(const float4*)(sdp + js);
    s.sdb = *(const float4*)(sdp + js + 4);
#pragma unroll
    for (int ni = 0; ni < 4; ++ni) s.bfr[ni] = *(const short8*)(hb[ni] + js);
}

__device__ __forceinline__ void consume_stage(
    const Stage& s, float ss, unsigned mb, float& lsum, f32x4* acc)
{
    const float sd[8] = {s.sda.x, s.sda.y, s.sda.z, s.sda.w,
                         s.sdb.x, s.sdb.y, s.sdb.z, s.sdb.w};
    float p[8];
#pragma unroll
    for (int t = 0; t < 8; ++t) {
        float x = ss + sd[t];
        x = fmaxf(x, 0.2f * x);                 // leaky_relu (alpha=0.2)
        p[t] = __builtin_amdgcn_exp2f(x);
    }
    if (mb) {                                    // ~1 zero in 8.4M entries
#pragma unroll
        for (int t = 0; t < 8; ++t)
            if ((mb >> t) & 1u) p[t] = 0.f;
    }
#pragma unroll
    for (int t = 0; t < 8; ++t) lsum += p[t];

    union { short8 v; __hip_bfloat162 h2[4]; } pk;
#pragma unroll
    for (int t = 0; t < 4; ++t)
        pk.h2[t] = __float22bfloat162_rn(make_float2(p[2 * t], p[2 * t + 1]));
#pragma unroll
    for (int ni = 0; ni < 4; ++ni)
        acc[ni] = __builtin_amdgcn_mfma_f32_16x16x32_bf16(pk.v, s.bfr[ni], acc[ni], 0, 0, 0);
}

__global__ __launch_bounds__(1024) void k2_attn(
    const unsigned short* __restrict__ hT, const float* __restrict__ ssT,
    const float* __restrict__ sdT, const unsigned char* __restrict__ zT,
    const float* __restrict__ b_gat, const float* __restrict__ gamma,
    const float* __restrict__ beta, float* __restrict__ out)
{
    __shared__ float accs[3][16][HH][64];   // 48 KB; bank = lane%32 (2-way, free)
    __shared__ float lsumx[3][HH][16];
    __shared__ float red1s[HH][16], red2s[HH][16];

    const int blk = blockIdx.x;             // B * (N/16)
    const int b  = blk >> 7;
    const int i0 = (blk & 127) << 4;
    const int tid  = threadIdx.x;
    const int wave = tid >> 6;
    const int h  = wave & 3;
    const int jq = wave >> 2;               // j-quarter: 512 j's each
    const int l  = tid & 63;
    const int lr = l & 15;                  // A row / B,D col in tile
    const int lq = l >> 4;                  // quad

    const float ss = ssT[(b * HH + h) * NN + i0 + lr];

    // whole j-loop's zero-mask for this lane: 16 bytes (byte it = step it)
    const uint4 mw = *(const uint4*)(zT + ((size_t)(b * NN + i0 + lr) << 8)
                                       + jq * 64 + lq * 16);

    f32x4 acc[4];
#pragma unroll
    for (int ni = 0; ni < 4; ++ni) acc[ni] = (f32x4){0.f, 0.f, 0.f, 0.f};
    float lsum = 0.f;

    const float* sdp  = sdT + (b * HH + h) * NN + jq * 512 + lq * 8;
    const unsigned short* hb[4];
#pragma unroll
    for (int ni = 0; ni < 4; ++ni)
        hb[ni] = hT + ((size_t)(b * HH + h) * CC + ni * 16 + lr) * NN + jq * 512 + lq * 8;

    // 16 steps of 32 j; 2-stage rotation, loads one full step ahead.
    // Fully unrolled 4x4 so mask-byte extraction is compile-time.
    Stage s0, s1;
    load_stage(s0, sdp, hb, 0);
#pragma unroll
    for (int w = 0; w < 4; ++w) {
        const unsigned mword = (w == 0) ? mw.x : (w == 1) ? mw.y
                             : (w == 2) ? mw.z : mw.w;
#pragma unroll
        for (int k = 0; k < 4; k += 2) {
            const int it = w * 4 + k;
            load_stage(s1, sdp, hb, (it + 1) * 32);
            consume_stage(s0, ss, (mword >> (k * 8)) & 0xffu, lsum, acc);
            if (it + 2 < 16) load_stage(s0, sdp, hb, (it + 2) * 32);
            consume_stage(s1, ss, (mword >> ((k + 1) * 8)) & 0xffu, lsum, acc);
        }
    }

    // reduce lsum over quads: every lane holds row-lsum for row lr (this jq)
    lsum += __shfl_xor(lsum, 16, 64);
    lsum += __shfl_xor(lsum, 32, 64);

    if (jq > 0) {
        if (lq == 0) lsumx[jq - 1][h][lr] = lsum;
#pragma unroll
        for (int ni = 0; ni < 4; ++ni)
#pragma unroll
            for (int r = 0; r < 4; ++r)
                accs[jq - 1][ni * 4 + r][h][l] = acc[ni][r];
    }
    __syncthreads();

    if (jq == 0) {
        const float lcomb = lsum + lsumx[0][h][lr] + lsumx[1][h][lr] + lsumx[2][h][lr];
        float lrow[4];
#pragma unroll
        for (int r = 0; r < 4; ++r) lrow[r] = __shfl(lcomb, lq * 4 + r, 64);

        float bg[4];
#pragma unroll
        for (int ni = 0; ni < 4; ++ni) bg[ni] = b_gat[h * 64 + ni * 16 + lr];

        float vals[4][4];   // [ni][r]
        float s1[4] = {0.f, 0.f, 0.f, 0.f}, s2[4] = {0.f, 0.f, 0.f, 0.f};
#pragma unroll
        for (int ni = 0; ni < 4; ++ni)
#pragma unroll
            for (int r = 0; r < 4; ++r) {
                float a = acc[ni][r] + accs[0][ni * 4 + r][h][l]
                        + accs[1][ni * 4 + r][h][l] + accs[2][ni * 4 + r][h][l];
                float v = a / lrow[r] + bg[ni];
                v = (v > 0.f) ? v : (__expf(v) - 1.f);   // ELU
                vals[ni][r] = v;
                s1[r] += v;
                s2[r] += v * v;
            }
        // reduce over the 16 col-lanes (rows are per-quad)
#pragma unroll
        for (int m = 1; m <= 8; m <<= 1)
#pragma unroll
            for (int r = 0; r < 4; ++r) {
                s1[r] += __shfl_xor(s1[r], m, 64);
                s2[r] += __shfl_xor(s2[r], m, 64);
            }
        if (lr == 0)
#pragma unroll
            for (int r = 0; r < 4; ++r) {
                red1s[h][lq * 4 + r] = s1[r];
                red2s[h][lq * 4 + r] = s2[r];
            }
        __syncthreads();

        const float gm[4] = {gamma[h * 64 + lr], gamma[h * 64 + 16 + lr],
                             gamma[h * 64 + 32 + lr], gamma[h * 64 + 48 + lr]};
        const float bm[4] = {beta[h * 64 + lr], beta[h * 64 + 16 + lr],
                             beta[h * 64 + 32 + lr], beta[h * 64 + 48 + lr]};
#pragma unroll
        for (int r = 0; r < 4; ++r) {
            const int row = lq * 4 + r;
            float S1 = red1s[0][row] + red1s[1][row] + red1s[2][row] + red1s[3][row];
            float S2 = red2s[0][row] + red2s[1][row] + red2s[2][row] + red2s[3][row];
            float mu  = S1 * (1.f / HC);
            float var = S2 * (1.f / HC) - mu * mu;
            float inv = rsqrtf(var + 1e-3f);
            float* op = out + (size_t)(b * NN + i0 + row) * HC + h * 64 + lr;
#pragma unroll
            for (int ni = 0; ni < 4; ++ni)
                op[ni * 16] = (vals[ni][r] - mu) * inv * gm[ni] + bm[ni];
        }
    } else {
        __syncthreads();   // matched barrier for jq>0 waves
    }
}

extern "C" void kernel_launch(void* const* d_in, const int* in_sizes, int n_in,
                              void* d_out, int out_size, void* d_ws, size_t ws_size,
                              hipStream_t stream)
{
    const float* X     = (const float*)d_in[0];
    const float* Adj   = (const float*)d_in[1];
    // d_in[2..4] = E, W_edge, b_edge: unused (see header).
    const float* Wg    = (const float*)d_in[5];
    const float* a_src = (const float*)d_in[6];
    const float* a_dst = (const float*)d_in[7];
    const float* b_gat = (const float*)d_in[8];
    const float* gam   = (const float*)d_in[9];
    const float* bet   = (const float*)d_in[10];
    float* out = (float*)d_out;

    const size_t hT_elems = (size_t)BB * HH * CC * NN;   // ushort (2 MB)
    const size_t ss_elems = (size_t)BB * HH * NN;        // float

    unsigned short* hT = (unsigned short*)d_ws;
    float* ssT = (float*)(hT + hT_elems);
    float* sdT = ssT + ss_elems;
    unsigned char* zT = (unsigned char*)(sdT + ss_elems); // 1 MB bitmask

    k1_proj<<<BB * NN / TN, 256, 0, stream>>>(X, Adj, Wg, a_src, a_dst, hT, ssT, sdT, zT);
    k2_attn<<<BB * (NN / 16), 1024, 0, stream>>>(hT, ssT, sdT, zT, b_gat, gam, bet, out);
}

// Round 2
// 380.660 us; speedup vs baseline: 1.6169x; 1.6169x over previous
//
#include <hip/hip_runtime.h>
#include <hip/hip_bf16.h>

// DynamicGATLayer on MI355X — R6: R5's Adj==0 bitmask kept, spill fixed.
// B=2, N=2048, F=128, FE=8, H=4, C=64, HC=256.
//
// Simplifications (verified passing R1-R5):
//  - A * sigmoid(E.W_edge+b) == 0  <=>  A == 0 (sigmoid in (0.1,0.9)), so
//    E/W_edge/b_edge are never read.
//  - |leaky(ss+sd)| <~ 6 -> exp without max-subtraction is safe in fp32;
//    masked entries are exactly 0 both here and in the reference.
//  - ss/sd pre-scaled by log2(e): exp(leaky(x)) = exp2(leaky(x*log2e)).
//  - Adj values never needed in k2 — only the (A==0) predicate. k1 sweeps Adj
//    once (coalesced, 33.5 MB) into a 1-bit-per-edge mask zT (1 MB), laid out
//    [row][jq][lq][step] so a k2 lane loads its whole j-loop mask as ONE 16B load.
//
// R6 deltas vs R5 (615 us — REGRESSION, root-caused):
//  - R5's fully-unrolled 4x4 j-loop + launch_bounds(1024) let the compiler cap
//    VGPRs at 64 and spill both Stage structs to scratch: rocprof showed k2 at
//    320 us, WRITE_SIZE 621 MB / FETCH_SIZE 320 MB (vs ~5 MB real footprint),
//    VALUBusy 2.5%. Fix:
//    (a) __launch_bounds__(1024, 4): grid = 256 blocks = exactly 1 block/CU,
//        so 4 waves/EU is the true occupancy; VGPR cap rises 64 -> 128.
//    (b) revert to R4's rolled `#pragma unroll 2` 16-step two-stage rotation
//        (measured-good). Mask bytes extracted with runtime 64-bit shifts
//        (registers only — no compile-time indexing needed, no scratch).

#define BB 2
#define NN 2048
#define FF 128
#define HH 4
#define CC 64
#define HC 256
#define TN 8      // node rows per block, K1
#define LOG2E 1.4426950408889634f

typedef __attribute__((ext_vector_type(8))) short short8;
typedef __attribute__((ext_vector_type(4))) float f32x4;

__device__ __forceinline__ float wave_sum(float v) {
#pragma unroll
    for (int m = 32; m >= 1; m >>= 1) v += __shfl_xor(v, m, 64);
    return v;
}

__device__ __forceinline__ unsigned short bf16rne(float x) {
    unsigned u = __float_as_uint(x);
    return (unsigned short)((u + 0x7fffu + ((u >> 16) & 1u)) >> 16);
}

// ---------------- K1 ----------------
__global__ __launch_bounds__(256) void k1_proj(
    const float* __restrict__ X, const float* __restrict__ Adj,
    const float* __restrict__ Wg,
    const float* __restrict__ a_src, const float* __restrict__ a_dst,
    unsigned short* __restrict__ hT, float* __restrict__ ssT,
    float* __restrict__ sdT, unsigned char* __restrict__ zT)
{
    __shared__ float sX[TN][FF];
    const int blk = blockIdx.x;               // B*N/TN blocks
    const int b  = blk / (NN / TN);
    const int n0 = (blk % (NN / TN)) * TN;
    const int tid = threadIdx.x;
    const int h = tid >> 6, c = tid & 63;

    for (int idx = tid; idx < TN * FF; idx += 256) {
        int r = idx >> 7, f = idx & 127;
        sX[r][f] = X[(size_t)(b * NN + n0 + r) * FF + f];
    }
    __syncthreads();

    float hv[TN];
#pragma unroll
    for (int r = 0; r < TN; ++r) hv[r] = 0.f;

#pragma unroll 4
    for (int f4 = 0; f4 < FF / 4; ++f4) {
        const int f = f4 * 4;
        const float w0 = Wg[(h * FF + f + 0) * CC + c];
        const float w1 = Wg[(h * FF + f + 1) * CC + c];
        const float w2 = Wg[(h * FF + f + 2) * CC + c];
        const float w3 = Wg[(h * FF + f + 3) * CC + c];
#pragma unroll
        for (int r = 0; r < TN; ++r) {
            float4 x4 = *(const float4*)&sX[r][f];
            hv[r] = fmaf(x4.x, w0, hv[r]);
            hv[r] = fmaf(x4.y, w1, hv[r]);
            hv[r] = fmaf(x4.z, w2, hv[r]);
            hv[r] = fmaf(x4.w, w3, hv[r]);
        }
    }

    // hT[b][h][c][n], 8 consecutive n per thread -> one 16B store
    union { short8 v; unsigned short u[8]; } pk;
#pragma unroll
    for (int r = 0; r < TN; ++r) pk.u[r] = bf16rne(hv[r]);
    *(short8*)&hT[((size_t)(b * HH + h) * CC + c) * NN + n0] = pk.v;

    const float as = a_src[tid];
    const float ad = a_dst[tid];
#pragma unroll
    for (int r = 0; r < TN; ++r) {
        const int n = n0 + r;
        float s1 = wave_sum(hv[r] * as);
        float s2 = wave_sum(hv[r] * ad);
        if (c == 0) {
            ssT[(b * HH + h) * NN + n] = s1 * LOG2E;
            sdT[(b * HH + h) * NN + n] = s2 * LOG2E;
        }
    }

    // ---- Adj zero-bitmask sweep: rows n0..n0+7, all 2048 j ----
    // thread t: row r = t>>5, segment s = t&31 -> j in [s*64, s*64+64).
    // byte jb = j/8 stored at row-offset (jb>>6)*64 + (jb&3)*16 + ((jb&63)>>2),
    // i.e. zT[row][jq][lq][step] so a k2 lane's 16 step-bytes are contiguous.
    {
        const int r = tid >> 5;
        const int s = tid & 31;
        const size_t row = (size_t)(b * NN + n0 + r);
        const float* ap = Adj + row * NN + s * 64;
        unsigned char* zp = zT + (row << 8);
#pragma unroll
        for (int k = 0; k < 8; ++k) {
            float4 a0 = *(const float4*)(ap + k * 8);
            float4 a1 = *(const float4*)(ap + k * 8 + 4);
            unsigned m = 0u;
            m |= (a0.x == 0.f) ? 1u   : 0u;
            m |= (a0.y == 0.f) ? 2u   : 0u;
            m |= (a0.z == 0.f) ? 4u   : 0u;
            m |= (a0.w == 0.f) ? 8u   : 0u;
            m |= (a1.x == 0.f) ? 16u  : 0u;
            m |= (a1.y == 0.f) ? 32u  : 0u;
            m |= (a1.z == 0.f) ? 64u  : 0u;
            m |= (a1.w == 0.f) ? 128u : 0u;
            const int jb = s * 8 + k;
            const int jq = jb >> 6, rem = jb & 63;
            const int it = rem >> 2, lq = rem & 3;
            zp[jq * 64 + lq * 16 + it] = (unsigned char)m;
        }
    }
}

// ---------------- K2 ----------------
struct Stage {
    float4 sda, sdb;  // sd, 8 floats
    short8 bfr[4];    // hT B-frags
};

__device__ __forceinline__ void load_stage(
    Stage& s, const float* sdp, const unsigned short* const* hb, int js)
{
    s.sda = *(const float4*)(sdp + js);
    s.sdb = *(const float4*)(sdp + js + 4);
#pragma unroll
    for (int ni = 0; ni < 4; ++ni) s.bfr[ni] = *(const short8*)(hb[ni] + js);
}

__device__ __forceinline__ void consume_stage(
    const Stage& s, float ss, unsigned mb, float& lsum, f32x4* acc)
{
    const float sd[8] = {s.sda.x, s.sda.y, s.sda.z, s.sda.w,
                         s.sdb.x, s.sdb.y, s.sdb.z, s.sdb.w};
    float p[8];
#pragma unroll
    for (int t = 0; t < 8; ++t) {
        float x = ss + sd[t];
        x = fmaxf(x, 0.2f * x);                 // leaky_relu (alpha=0.2)
        p[t] = __builtin_amdgcn_exp2f(x);
    }
    if (mb) {                                    // ~1 zero in 8.4M entries
#pragma unroll
        for (int t = 0; t < 8; ++t)
            if ((mb >> t) & 1u) p[t] = 0.f;
    }
#pragma unroll
    for (int t = 0; t < 8; ++t) lsum += p[t];

    union { short8 v; __hip_bfloat162 h2[4]; } pk;
#pragma unroll
    for (int t = 0; t < 4; ++t)
        pk.h2[t] = __float22bfloat162_rn(make_float2(p[2 * t], p[2 * t + 1]));
#pragma unroll
    for (int ni = 0; ni < 4; ++ni)
        acc[ni] = __builtin_amdgcn_mfma_f32_16x16x32_bf16(pk.v, s.bfr[ni], acc[ni], 0, 0, 0);
}

__global__ __launch_bounds__(1024, 4) void k2_attn(
    const unsigned short* __restrict__ hT, const float* __restrict__ ssT,
    const float* __restrict__ sdT, const unsigned char* __restrict__ zT,
    const float* __restrict__ b_gat, const float* __restrict__ gamma,
    const float* __restrict__ beta, float* __restrict__ out)
{
    __shared__ float accs[3][16][HH][64];   // 48 KB; bank = lane%32 (2-way, free)
    __shared__ float lsumx[3][HH][16];
    __shared__ float red1s[HH][16], red2s[HH][16];

    const int blk = blockIdx.x;             // B * (N/16)
    const int b  = blk >> 7;
    const int i0 = (blk & 127) << 4;
    const int tid  = threadIdx.x;
    const int wave = tid >> 6;
    const int h  = wave & 3;
    const int jq = wave >> 2;               // j-quarter: 512 j's each
    const int l  = tid & 63;
    const int lr = l & 15;                  // A row / B,D col in tile
    const int lq = l >> 4;                  // quad

    const float ss = ssT[(b * HH + h) * NN + i0 + lr];

    // whole j-loop's zero-mask for this lane: 16 bytes (byte it = step it)
    const uint4 mw = *(const uint4*)(zT + ((size_t)(b * NN + i0 + lr) << 8)
                                       + jq * 64 + lq * 16);
    const unsigned long long mlo = ((unsigned long long)mw.y << 32) | mw.x; // steps 0..7
    const unsigned long long mhi = ((unsigned long long)mw.w << 32) | mw.z; // steps 8..15

    f32x4 acc[4];
#pragma unroll
    for (int ni = 0; ni < 4; ++ni) acc[ni] = (f32x4){0.f, 0.f, 0.f, 0.f};
    float lsum = 0.f;

    const float* sdp  = sdT + (b * HH + h) * NN + jq * 512 + lq * 8;
    const unsigned short* hb[4];
#pragma unroll
    for (int ni = 0; ni < 4; ++ni)
        hb[ni] = hT + ((size_t)(b * HH + h) * CC + ni * 16 + lr) * NN + jq * 512 + lq * 8;

    // 16 steps of 32 j; 2-stage rotation, loads one full step ahead (R4 structure).
    Stage s0, s1;
    load_stage(s0, sdp, hb, 0);
#pragma unroll 2
    for (int it = 0; it < 16; it += 2) {
        const unsigned long long msel = (it & 8) ? mhi : mlo;
        const int sh = (it & 7) * 8;                     // it even: sh, sh+8 same word
        const unsigned mb0 = (unsigned)(msel >> sh) & 0xffu;
        const unsigned mb1 = (unsigned)(msel >> (sh + 8)) & 0xffu;
        load_stage(s1, sdp, hb, (it + 1) * 32);
        consume_stage(s0, ss, mb0, lsum, acc);
        if (it + 2 < 16) load_stage(s0, sdp, hb, (it + 2) * 32);
        consume_stage(s1, ss, mb1, lsum, acc);
    }

    // reduce lsum over quads: every lane holds row-lsum for row lr (this jq)
    lsum += __shfl_xor(lsum, 16, 64);
    lsum += __shfl_xor(lsum, 32, 64);

    if (jq > 0) {
        if (lq == 0) lsumx[jq - 1][h][lr] = lsum;
#pragma unroll
        for (int ni = 0; ni < 4; ++ni)
#pragma unroll
            for (int r = 0; r < 4; ++r)
                accs[jq - 1][ni * 4 + r][h][l] = acc[ni][r];
    }
    __syncthreads();

    if (jq == 0) {
        const float lcomb = lsum + lsumx[0][h][lr] + lsumx[1][h][lr] + lsumx[2][h][lr];
        float lrow[4];
#pragma unroll
        for (int r = 0; r < 4; ++r) lrow[r] = __shfl(lcomb, lq * 4 + r, 64);

        float bg[4];
#pragma unroll
        for (int ni = 0; ni < 4; ++ni) bg[ni] = b_gat[h * 64 + ni * 16 + lr];

        float vals[4][4];   // [ni][r]
        float s1[4] = {0.f, 0.f, 0.f, 0.f}, s2[4] = {0.f, 0.f, 0.f, 0.f};
#pragma unroll
        for (int ni = 0; ni < 4; ++ni)
#pragma unroll
            for (int r = 0; r < 4; ++r) {
                float a = acc[ni][r] + accs[0][ni * 4 + r][h][l]
                        + accs[1][ni * 4 + r][h][l] + accs[2][ni * 4 + r][h][l];
                float v = a / lrow[r] + bg[ni];
                v = (v > 0.f) ? v : (__expf(v) - 1.f);   // ELU
                vals[ni][r] = v;
                s1[r] += v;
                s2[r] += v * v;
            }
        // reduce over the 16 col-lanes (rows are per-quad)
#pragma unroll
        for (int m = 1; m <= 8; m <<= 1)
#pragma unroll
            for (int r = 0; r < 4; ++r) {
                s1[r] += __shfl_xor(s1[r], m, 64);
                s2[r] += __shfl_xor(s2[r], m, 64);
            }
        if (lr == 0)
#pragma unroll
            for (int r = 0; r < 4; ++r) {
                red1s[h][lq * 4 + r] = s1[r];
                red2s[h][lq * 4 + r] = s2[r];
            }
        __syncthreads();

        const float gm[4] = {gamma[h * 64 + lr], gamma[h * 64 + 16 + lr],
                             gamma[h * 64 + 32 + lr], gamma[h * 64 + 48 + lr]};
        const float bm[4] = {beta[h * 64 + lr], beta[h * 64 + 16 + lr],
                             beta[h * 64 + 32 + lr], beta[h * 64 + 48 + lr]};
#pragma unroll
        for (int r = 0; r < 4; ++r) {
            const int row = lq * 4 + r;
            float S1 = red1s[0][row] + red1s[1][row] + red1s[2][row] + red1s[3][row];
            float S2 = red2s[0][row] + red2s[1][row] + red2s[2][row] + red2s[3][row];
            float mu  = S1 * (1.f / HC);
            float var = S2 * (1.f / HC) - mu * mu;
            float inv = rsqrtf(var + 1e-3f);
            float* op = out + (size_t)(b * NN + i0 + row) * HC + h * 64 + lr;
#pragma unroll
            for (int ni = 0; ni < 4; ++ni)
                op[ni * 16] = (vals[ni][r] - mu) * inv * gm[ni] + bm[ni];
        }
    } else {
        __syncthreads();   // matched barrier for jq>0 waves
    }
}

extern "C" void kernel_launch(void* const* d_in, const int* in_sizes, int n_in,
                              void* d_out, int out_size, void* d_ws, size_t ws_size,
                              hipStream_t stream)
{
    const float* X     = (const float*)d_in[0];
    const float* Adj   = (const float*)d_in[1];
    // d_in[2..4] = E, W_edge, b_edge: unused (see header).
    const float* Wg    = (const float*)d_in[5];
    const float* a_src = (const float*)d_in[6];
    const float* a_dst = (const float*)d_in[7];
    const float* b_gat = (const float*)d_in[8];
    const float* gam   = (const float*)d_in[9];
    const float* bet   = (const float*)d_in[10];
    float* out = (float*)d_out;

    const size_t hT_elems = (size_t)BB * HH * CC * NN;   // ushort (2 MB)
    const size_t ss_elems = (size_t)BB * HH * NN;        // float

    unsigned short* hT = (unsigned short*)d_ws;
    float* ssT = (float*)(hT + hT_elems);
    float* sdT = ssT + ss_elems;
    unsigned char* zT = (unsigned char*)(sdT + ss_elems); // 1 MB bitmask

    k1_proj<<<BB * NN / TN, 256, 0, stream>>>(X, Adj, Wg, a_src, a_dst, hT, ssT, sdT, zT);
    k2_attn<<<BB * (NN / 16), 1024, 0, stream>>>(hT, ssT, sdT, zT, b_gat, gam, bet, out);
}

// Round 3
// 369.914 us; speedup vs baseline: 1.6639x; 1.0290x over previous
//
#include <hip/hip_runtime.h>
#include <hip/hip_bf16.h>

// DynamicGATLayer on MI355X — R7: k2 loop de-pressurized (hT re-layout, lean
// 2-stage rotation, branch-free mask); k1 LDS staging dropped (scalar X loads).
// B=2, N=2048, F=128, FE=8, H=4, C=64, HC=256.
//
// Simplifications (verified passing R1-R6):
//  - A * sigmoid(E.W_edge+b) == 0  <=>  A == 0 (sigmoid in (0.1,0.9)), so
//    E/W_edge/b_edge are never read.
//  - |leaky(ss+sd)| <~ 6 -> exp without max-subtraction is safe in fp32.
//  - ss/sd pre-scaled by log2(e): exp(leaky(x)) = exp2(leaky(x*log2e)).
//  - Adj==0 predicate precomputed in k1 as bitmask zT (1 MB), layout
//    [row][jq][lq][step]; one 16B load gives a k2 lane its whole j-loop mask.
//
// Per-iteration budget (R5/R6 cross-fit): 1-GiB ws fill 160us + input restores
// + gaps ~135us (fixed) + k1 (~15us) + k2 (85.7us in R6 vs ~12-15us floor).
// R7 attacks k2's ~70us of stall, suspected register/issue pressure:
//  - hT re-layout [b][h][jb=n/8][c][8]: a lane's 4 ni-frags sit at byte
//    offsets 0/256/512/768 from ONE base -> 4 imm-offset loads, 1 add/step
//    (was: 4 separate 64-bit pointer chains).
//  - explicit 2-stage rotation under #pragma unroll 1: consume(s0); refill
//    s0<-it+2; consume(s1); refill s1<-it+3. ~90 VGPR live, hard under the
//    128 cap from __launch_bounds__(1024,4) -> no spill, no scheduler balloon.
//  - mask via v_cndmask (p = bit ? 0 : exp), no divergent branch.
// k1: X[r][f] is block-uniform -> read straight from global (s_load path),
// dropping the sX LDS staging + barrier entirely.

#define BB 2
#define NN 2048
#define FF 128
#define HH 4
#define CC 64
#define HC 256
#define TN 8      // node rows per block, K1
#define JB (NN / 8)   // 256 j-blocks of 8
#define LOG2E 1.4426950408889634f

typedef __attribute__((ext_vector_type(8))) short short8;
typedef __attribute__((ext_vector_type(4))) float f32x4;

__device__ __forceinline__ float wave_sum(float v) {
#pragma unroll
    for (int m = 32; m >= 1; m >>= 1) v += __shfl_xor(v, m, 64);
    return v;
}

__device__ __forceinline__ unsigned short bf16rne(float x) {
    unsigned u = __float_as_uint(x);
    return (unsigned short)((u + 0x7fffu + ((u >> 16) & 1u)) >> 16);
}

// ---------------- K1 ----------------
__global__ __launch_bounds__(256) void k1_proj(
    const float* __restrict__ X, const float* __restrict__ Adj,
    const float* __restrict__ Wg,
    const float* __restrict__ a_src, const float* __restrict__ a_dst,
    unsigned short* __restrict__ hT, float* __restrict__ ssT,
    float* __restrict__ sdT, unsigned char* __restrict__ zT)
{
    const int blk = blockIdx.x;               // B*N/TN blocks
    const int b  = blk / (NN / TN);
    const int n0 = (blk % (NN / TN)) * TN;
    const int tid = threadIdx.x;
    const int h = tid >> 6, c = tid & 63;

    float hv[TN];
#pragma unroll
    for (int r = 0; r < TN; ++r) hv[r] = 0.f;

    const float* xp = X + (size_t)(b * NN + n0) * FF;   // block-uniform base

#pragma unroll 4
    for (int f4 = 0; f4 < FF / 4; ++f4) {
        const int f = f4 * 4;
        const float w0 = Wg[(h * FF + f + 0) * CC + c];
        const float w1 = Wg[(h * FF + f + 1) * CC + c];
        const float w2 = Wg[(h * FF + f + 2) * CC + c];
        const float w3 = Wg[(h * FF + f + 3) * CC + c];
#pragma unroll
        for (int r = 0; r < TN; ++r) {
            float4 x4 = *(const float4*)(xp + r * FF + f);   // wave-uniform -> s_load
            hv[r] = fmaf(x4.x, w0, hv[r]);
            hv[r] = fmaf(x4.y, w1, hv[r]);
            hv[r] = fmaf(x4.z, w2, hv[r]);
            hv[r] = fmaf(x4.w, w3, hv[r]);
        }
    }

    // hT[b][h][jb][c][8]: thread (h,c) owns jb = n0/8, 8 consecutive n -> one
    // 16B store; lanes (consecutive c) -> contiguous 1KB per wave.
    union { short8 v; unsigned short u[8]; } pk;
#pragma unroll
    for (int r = 0; r < TN; ++r) pk.u[r] = bf16rne(hv[r]);
    *(short8*)&hT[((((size_t)b * HH + h) * JB + (n0 >> 3)) * CC + c) * 8] = pk.v;

    const float as = a_src[tid];
    const float ad = a_dst[tid];
#pragma unroll
    for (int r = 0; r < TN; ++r) {
        const int n = n0 + r;
        float s1 = wave_sum(hv[r] * as);
        float s2 = wave_sum(hv[r] * ad);
        if (c == 0) {
            ssT[(b * HH + h) * NN + n] = s1 * LOG2E;
            sdT[(b * HH + h) * NN + n] = s2 * LOG2E;
        }
    }

    // ---- Adj zero-bitmask sweep: rows n0..n0+7, all 2048 j ----
    // thread t: row r = t>>5, segment s = t&31 -> j in [s*64, s*64+64).
    // byte jb stored at row-offset jq*64 + lq*16 + step, matching k2's read.
    {
        const int r = tid >> 5;
        const int s = tid & 31;
        const size_t row = (size_t)(b * NN + n0 + r);
        const float* ap = Adj + row * NN + s * 64;
        unsigned char* zp = zT + (row << 8);
#pragma unroll
        for (int k = 0; k < 8; ++k) {
            float4 a0 = *(const float4*)(ap + k * 8);
            float4 a1 = *(const float4*)(ap + k * 8 + 4);
            unsigned m = 0u;
            m |= (a0.x == 0.f) ? 1u   : 0u;
            m |= (a0.y == 0.f) ? 2u   : 0u;
            m |= (a0.z == 0.f) ? 4u   : 0u;
            m |= (a0.w == 0.f) ? 8u   : 0u;
            m |= (a1.x == 0.f) ? 16u  : 0u;
            m |= (a1.y == 0.f) ? 32u  : 0u;
            m |= (a1.z == 0.f) ? 64u  : 0u;
            m |= (a1.w == 0.f) ? 128u : 0u;
            const int jb = s * 8 + k;
            const int jq = jb >> 6, rem = jb & 63;
            const int it = rem >> 2, lq = rem & 3;
            zp[jq * 64 + lq * 16 + it] = (unsigned char)m;
        }
    }
}

// ---------------- K2 ----------------
struct Stage {
    float4 sda, sdb;  // sd, 8 floats
    short8 bfr[4];    // hT B-frags
};

__device__ __forceinline__ void load_stage(
    Stage& s, const float* sdp, const unsigned short* hb, int it)
{
    const int js = it * 32;
    s.sda = *(const float4*)(sdp + js);
    s.sdb = *(const float4*)(sdp + js + 4);
    const unsigned short* hp = hb + it * 2048;   // 4 jb per step * 64c * 8
#pragma unroll
    for (int ni = 0; ni < 4; ++ni)
        s.bfr[ni] = *(const short8*)(hp + ni * 128);   // +256B imm offsets
}

__device__ __forceinline__ void consume_stage(
    const Stage& s, float ss, unsigned mb, float& lsum, f32x4* acc)
{
    const float sd[8] = {s.sda.x, s.sda.y, s.sda.z, s.sda.w,
                         s.sdb.x, s.sdb.y, s.sdb.z, s.sdb.w};
    float p[8];
#pragma unroll
    for (int t = 0; t < 8; ++t) {
        float x = ss + sd[t];
        x = fmaxf(x, 0.2f * x);                 // leaky_relu (alpha=0.2)
        float pv = __builtin_amdgcn_exp2f(x);
        p[t] = ((mb >> t) & 1u) ? 0.f : pv;     // v_cndmask, no branch
        lsum += p[t];
    }
    union { short8 v; __hip_bfloat162 h2[4]; } pk;
#pragma unroll
    for (int t = 0; t < 4; ++t)
        pk.h2[t] = __float22bfloat162_rn(make_float2(p[2 * t], p[2 * t + 1]));
#pragma unroll
    for (int ni = 0; ni < 4; ++ni)
        acc[ni] = __builtin_amdgcn_mfma_f32_16x16x32_bf16(pk.v, s.bfr[ni], acc[ni], 0, 0, 0);
}

__global__ __launch_bounds__(1024, 4) void k2_attn(
    const unsigned short* __restrict__ hT, const float* __restrict__ ssT,
    const float* __restrict__ sdT, const unsigned char* __restrict__ zT,
    const float* __restrict__ b_gat, const float* __restrict__ gamma,
    const float* __restrict__ beta, float* __restrict__ out)
{
    __shared__ float accs[3][16][HH][64];   // 48 KB; bank = lane%32 (2-way, free)
    __shared__ float lsumx[3][HH][16];
    __shared__ float red1s[HH][16], red2s[HH][16];

    const int blk = blockIdx.x;             // B * (N/16)
    const int b  = blk >> 7;
    const int i0 = (blk & 127) << 4;
    const int tid  = threadIdx.x;
    const int wave = tid >> 6;
    const int h  = wave & 3;
    const int jq = wave >> 2;               // j-quarter: 512 j's each
    const int l  = tid & 63;
    const int lr = l & 15;                  // A row / B,D col in tile
    const int lq = l >> 4;                  // quad

    const float ss = ssT[(b * HH + h) * NN + i0 + lr];

    // whole j-loop's zero-mask for this lane: 16 bytes (byte it = step it)
    const uint4 mw = *(const uint4*)(zT + ((size_t)(b * NN + i0 + lr) << 8)
                                       + jq * 64 + lq * 16);
    const unsigned long long mlo = ((unsigned long long)mw.y << 32) | mw.x; // steps 0..7
    const unsigned long long mhi = ((unsigned long long)mw.w << 32) | mw.z; // steps 8..15

    f32x4 acc[4];
#pragma unroll
    for (int ni = 0; ni < 4; ++ni) acc[ni] = (f32x4){0.f, 0.f, 0.f, 0.f};
    float lsum = 0.f;

    const float* sdp = sdT + (b * HH + h) * NN + jq * 512 + lq * 8;
    // hT[b][h][jb][c][8]; lane base: jb = jq*64 + lq, c = lr (+ni*16 via imm)
    const unsigned short* hb =
        hT + ((((size_t)b * HH + h) * JB + jq * 64 + lq) * CC + lr) * 8;

    // 16 steps of 32 j; explicit 2-stage rotation, distance-2 prefetch.
    Stage s0, s1;
    load_stage(s0, sdp, hb, 0);
    load_stage(s1, sdp, hb, 1);
#pragma unroll 1
    for (int it = 0; it < 16; it += 2) {
        const unsigned long long msel = (it & 8) ? mhi : mlo;
        const int sh = (it & 7) * 8;
        const unsigned mb0 = (unsigned)(msel >> sh) & 0xffu;
        const unsigned mb1 = (unsigned)(msel >> (sh + 8)) & 0xffu;
        consume_stage(s0, ss, mb0, lsum, acc);
        if (it + 2 < 16) load_stage(s0, sdp, hb, it + 2);
        consume_stage(s1, ss, mb1, lsum, acc);
        if (it + 3 < 16) load_stage(s1, sdp, hb, it + 3);
    }

    // reduce lsum over quads: every lane holds row-lsum for row lr (this jq)
    lsum += __shfl_xor(lsum, 16, 64);
    lsum += __shfl_xor(lsum, 32, 64);

    if (jq > 0) {
        if (lq == 0) lsumx[jq - 1][h][lr] = lsum;
#pragma unroll
        for (int ni = 0; ni < 4; ++ni)
#pragma unroll
            for (int r = 0; r < 4; ++r)
                accs[jq - 1][ni * 4 + r][h][l] = acc[ni][r];
    }
    __syncthreads();

    if (jq == 0) {
        const float lcomb = lsum + lsumx[0][h][lr] + lsumx[1][h][lr] + lsumx[2][h][lr];
        float lrow[4];
#pragma unroll
        for (int r = 0; r < 4; ++r) lrow[r] = __shfl(lcomb, lq * 4 + r, 64);

        float bg[4];
#pragma unroll
        for (int ni = 0; ni < 4; ++ni) bg[ni] = b_gat[h * 64 + ni * 16 + lr];

        float vals[4][4];   // [ni][r]
        float s1[4] = {0.f, 0.f, 0.f, 0.f}, s2[4] = {0.f, 0.f, 0.f, 0.f};
#pragma unroll
        for (int ni = 0; ni < 4; ++ni)
#pragma unroll
            for (int r = 0; r < 4; ++r) {
                float a = acc[ni][r] + accs[0][ni * 4 + r][h][l]
                        + accs[1][ni * 4 + r][h][l] + accs[2][ni * 4 + r][h][l];
                float v = a / lrow[r] + bg[ni];
                v = (v > 0.f) ? v : (__expf(v) - 1.f);   // ELU
                vals[ni][r] = v;
                s1[r] += v;
                s2[r] += v * v;
            }
        // reduce over the 16 col-lanes (rows are per-quad)
#pragma unroll
        for (int m = 1; m <= 8; m <<= 1)
#pragma unroll
            for (int r = 0; r < 4; ++r) {
                s1[r] += __shfl_xor(s1[r], m, 64);
                s2[r] += __shfl_xor(s2[r], m, 64);
            }
        if (lr == 0)
#pragma unroll
            for (int r = 0; r < 4; ++r) {
                red1s[h][lq * 4 + r] = s1[r];
                red2s[h][lq * 4 + r] = s2[r];
            }
        __syncthreads();

        const float gm[4] = {gamma[h * 64 + lr], gamma[h * 64 + 16 + lr],
                             gamma[h * 64 + 32 + lr], gamma[h * 64 + 48 + lr]};
        const float bm[4] = {beta[h * 64 + lr], beta[h * 64 + 16 + lr],
                             beta[h * 64 + 32 + lr], beta[h * 64 + 48 + lr]};
#pragma unroll
        for (int r = 0; r < 4; ++r) {
            const int row = lq * 4 + r;
            float S1 = red1s[0][row] + red1s[1][row] + red1s[2][row] + red1s[3][row];
            float S2 = red2s[0][row] + red2s[1][row] + red2s[2][row] + red2s[3][row];
            float mu  = S1 * (1.f / HC);
            float var = S2 * (1.f / HC) - mu * mu;
            float inv = rsqrtf(var + 1e-3f);
            float* op = out + (size_t)(b * NN + i0 + row) * HC + h * 64 + lr;
#pragma unroll
            for (int ni = 0; ni < 4; ++ni)
                op[ni * 16] = (vals[ni][r] - mu) * inv * gm[ni] + bm[ni];
        }
    } else {
        __syncthreads();   // matched barrier for jq>0 waves
    }
}

extern "C" void kernel_launch(void* const* d_in, const int* in_sizes, int n_in,
                              void* d_out, int out_size, void* d_ws, size_t ws_size,
                              hipStream_t stream)
{
    const float* X     = (const float*)d_in[0];
    const float* Adj   = (const float*)d_in[1];
    // d_in[2..4] = E, W_edge, b_edge: unused (see header).
    const float* Wg    = (const float*)d_in[5];
    const float* a_src = (const float*)d_in[6];
    const float* a_dst = (const float*)d_in[7];
    const float* b_gat = (const float*)d_in[8];
    const float* gam   = (const float*)d_in[9];
    const float* bet   = (const float*)d_in[10];
    float* out = (float*)d_out;

    const size_t hT_elems = (size_t)BB * HH * CC * NN;   // ushort (2 MB)
    const size_t ss_elems = (size_t)BB * HH * NN;        // float

    unsigned short* hT = (unsigned short*)d_ws;
    float* ssT = (float*)(hT + hT_elems);
    float* sdT = ssT + ss_elems;
    unsigned char* zT = (unsigned char*)(sdT + ss_elems); // 1 MB bitmask

    k1_proj<<<BB * NN / TN, 256, 0, stream>>>(X, Adj, Wg, a_src, a_dst, hT, ssT, sdT, zT);
    k2_attn<<<BB * (NN / 16), 1024, 0, stream>>>(hT, ssT, sdT, zT, b_gat, gam, bet, out);
}